// Round 3
// baseline (1866.464 us; speedup 1.0000x reference)
//
#include <hip/hip_runtime.h>
#include <hip/hip_bf16.h>

#define T_STEPS 512
#define BATCH   1024
#define HD1     80
#define HD2     100
#define NB      2       // batches per block

#define W1_DW   (HD1 / 2)              // 40 packed dwords per lstm1 row
#define W2_DW   ((HD1 + HD2) / 2)      // 90 packed dwords per lstm2 row
#define NR1     (4 * HD1)              // 320 rows
#define NR2     (4 * HD2)              // 400 rows

typedef _Float16 half2_t __attribute__((ext_vector_type(2)));

union HU { unsigned int u; half2_t h; };
static __device__ __forceinline__ half2_t bch(unsigned int u) { HU x; x.u = u; return x.h; }
static __device__ __forceinline__ unsigned int bcu(half2_t h) { HU x; x.h = h; return x.u; }

static __device__ __forceinline__ float dot2(half2_t a, half2_t b, float c) {
    return __builtin_amdgcn_fdot2(a, b, c, false);
}

static __device__ __forceinline__ unsigned int packh(float a, float b) {
    half2_t p; p.x = (_Float16)a; p.y = (_Float16)b; return bcu(p);
}

// ---------------------------------------------------------------------------
// Prep: pack weights to f16 dwords, transposed [dword][row] for coalescing.
// w1t[d*320 + j] = {W_hh1[j][2d], W_hh1[j][2d+1]}            d<40, j<320
// w2t[d*400 + j] = d<40 ? W_ih2 pair : W_hh2 pair (d-40)     d<90, j<400
// ---------------------------------------------------------------------------
__global__ __launch_bounds__(256)
void prep_kernel(const float* __restrict__ W_hh1,
                 const float* __restrict__ W_ih2,
                 const float* __restrict__ W_hh2,
                 unsigned int* __restrict__ w1t,
                 unsigned int* __restrict__ w2t)
{
    int i = blockIdx.x * 256 + threadIdx.x;
    if (i < W1_DW * NR1) {
        int d = i / NR1, j = i % NR1;
        w1t[i] = packh(W_hh1[j * HD1 + 2 * d], W_hh1[j * HD1 + 2 * d + 1]);
    } else if (i < W1_DW * NR1 + W2_DW * NR2) {
        int k = i - W1_DW * NR1;
        int d = k / NR2, j = k % NR2;
        unsigned int p;
        if (d < W1_DW)
            p = packh(W_ih2[j * HD1 + 2 * d], W_ih2[j * HD1 + 2 * d + 1]);
        else {
            int dd = d - W1_DW;
            p = packh(W_hh2[j * HD2 + 2 * dd], W_hh2[j * HD2 + 2 * dd + 1]);
        }
        w2t[k] = p;
    }
}

// ---------------------------------------------------------------------------
// Phase 1: LSTM layer 1. 512 blocks x 320 threads, 2 batches/block.
// Thread j owns gate-row j; weights = 40 uint regs. h state: uint4[20] in LDS,
// entry k4 = {b0_pair(4k4,4k4+1), b1_pair, b0_pair(4k4+2,4k4+3), b1_pair}.
// Writes relu(h1) f16 to ws, layout [t][b][k]. 2 barriers/step.
// ---------------------------------------------------------------------------
__global__ __launch_bounds__(NR1, 2)
void lstm1_kernel(const float* __restrict__ x,
                  const float* __restrict__ W_ih1,
                  const unsigned int* __restrict__ w1t,
                  const float* __restrict__ b_ih1,
                  const float* __restrict__ b_hh1,
                  _Float16* __restrict__ h1relu)
{
    const int j  = threadIdx.x;
    const int b0 = blockIdx.x * NB;
    const int q  = j / HD1;
    const int m  = j % HD1;

    unsigned int w[W1_DW];
#pragma unroll
    for (int d = 0; d < W1_DW; d++) w[d] = w1t[d * NR1 + j];
    const float wih  = W_ih1[j];
    const float bias = b_ih1[j] + b_hh1[j];

    __shared__ uint4  hp[HD1 / 4];
    __shared__ float2 gates[NR1];
    __shared__ float  xs[NB][T_STEPS];

    if (j < HD1 / 4) hp[j] = make_uint4(0u, 0u, 0u, 0u);
    for (int idx = j; idx < NB * T_STEPS; idx += NR1) {
        int b = idx >> 9, t = idx & (T_STEPS - 1);
        xs[b][t] = x[(size_t)(b0 + b) * T_STEPS + t];
    }
    float c0 = 0.f, c1 = 0.f;
    __syncthreads();

    for (int t = 0; t < T_STEPS; t++) {
        float acc0 = fmaf(wih, xs[0][t], bias);
        float acc1 = fmaf(wih, xs[1][t], bias);
#pragma unroll
        for (int k4 = 0; k4 < HD1 / 4; k4++) {
            uint4 U = hp[k4];
            acc0 = dot2(bch(w[2 * k4]),     bch(U.x), acc0);
            acc1 = dot2(bch(w[2 * k4]),     bch(U.y), acc1);
            acc0 = dot2(bch(w[2 * k4 + 1]), bch(U.z), acc0);
            acc1 = dot2(bch(w[2 * k4 + 1]), bch(U.w), acc1);
        }
        float z0 = (q == 2) ? 2.f * acc0 : acc0;
        float z1 = (q == 2) ? 2.f * acc1 : acc1;
        float s0 = 1.f / (1.f + __expf(-z0));
        float s1 = 1.f / (1.f + __expf(-z1));
        gates[j] = make_float2((q == 2) ? (2.f * s0 - 1.f) : s0,
                               (q == 2) ? (2.f * s1 - 1.f) : s1);
        __syncthreads();                       // gates ready

        if (j < HD1) {
            float2 gi = gates[m];
            float2 gf = gates[HD1 + m];
            float2 gg = gates[2 * HD1 + m];
            float2 go = gates[3 * HD1 + m];
            c0 = fmaf(gf.x, c0, gi.x * gg.x);
            c1 = fmaf(gf.y, c1, gi.y * gg.y);
            float t0 = 2.f / (1.f + __expf(-2.f * c0)) - 1.f;
            float t1 = 2.f / (1.f + __expf(-2.f * c1)) - 1.f;
            float h0 = go.x * t0;
            float h1 = go.y * t1;
            float h0a = __shfl_down(h0, 1, 64);
            float h0b = __shfl_down(h0, 2, 64);
            float h0c = __shfl_down(h0, 3, 64);
            float h1a = __shfl_down(h1, 1, 64);
            float h1b = __shfl_down(h1, 2, 64);
            float h1c = __shfl_down(h1, 3, 64);
            if ((m & 3) == 0) {
                hp[m >> 2] = make_uint4(packh(h0, h0a), packh(h1, h1a),
                                        packh(h0b, h0c), packh(h1b, h1c));
                uint2 r0 = make_uint2(packh(fmaxf(h0, 0.f), fmaxf(h0a, 0.f)),
                                      packh(fmaxf(h0b, 0.f), fmaxf(h0c, 0.f)));
                uint2 r1 = make_uint2(packh(fmaxf(h1, 0.f), fmaxf(h1a, 0.f)),
                                      packh(fmaxf(h1b, 0.f), fmaxf(h1c, 0.f)));
                *(uint2*)(h1relu + ((size_t)t * BATCH + b0)     * HD1 + m) = r0;
                *(uint2*)(h1relu + ((size_t)t * BATCH + b0 + 1) * HD1 + m) = r1;
            }
        }
        __syncthreads();                       // hp(t+1) ready
    }
}

// ---------------------------------------------------------------------------
// Phase 2: LSTM layer 2. 512 blocks x 448 threads, 2 batches/block.
// Thread j<400 owns gate-row j; weights = 90 uint regs (40 ih + 50 hh).
// h1/h2 state: uint4 LDS as in lstm1. h1 prefetched 1 step ahead (regs).
// 2 barriers/step.
// ---------------------------------------------------------------------------
__global__ __launch_bounds__(448, 4)
void lstm2_kernel(const _Float16* __restrict__ h1relu,
                  const unsigned int* __restrict__ w2t,
                  const float* __restrict__ b_ih2,
                  const float* __restrict__ b_hh2,
                  float* __restrict__ h2last)
{
    const int j  = threadIdx.x;
    const int b0 = blockIdx.x * NB;
    const bool rowActive = (j < NR2);
    const int q = j / HD2;
    const int m = j % HD2;

    unsigned int w[W2_DW];
    float bias = 0.f;
    if (rowActive) {
#pragma unroll
        for (int d = 0; d < W2_DW; d++) w[d] = w2t[d * NR2 + j];
        bias = b_ih2[j] + b_hh2[j];
    }

    __shared__ uint4  h1p[HD1 / 4];
    __shared__ uint4  h2p[HD2 / 4];
    __shared__ float2 gates[NR2];

    if (j < HD2 / 4) h2p[j] = make_uint4(0u, 0u, 0u, 0u);
    float c0 = 0.f, c1 = 0.f;

    // stagers: threads j<80, pb = batch, pk2 = dword index in 40-dword row
    const int pb = j / W1_DW, pk2 = j % W1_DW;
    const int sidx = 4 * (pk2 >> 1) + 2 * (pk2 & 1) + pb;  // dword slot in h1p
    unsigned int pf = 0;
    if (j < NB * W1_DW)
        pf = *(const unsigned int*)(h1relu + ((size_t)b0 + pb) * HD1 + 2 * pk2);

    for (int t = 0; t < T_STEPS; t++) {
        if (j < NB * W1_DW)
            ((unsigned int*)h1p)[sidx] = pf;   // stage h1(t)
        __syncthreads();                       // h1p(t) + h2p(t) ready

        if (j < NB * W1_DW && t + 1 < T_STEPS)
            pf = *(const unsigned int*)(h1relu +
                     ((size_t)(t + 1) * BATCH + b0 + pb) * HD1 + 2 * pk2);

        if (rowActive) {
            float acc0 = bias, acc1 = bias;
#pragma unroll
            for (int k4 = 0; k4 < HD1 / 4; k4++) {
                uint4 U = h1p[k4];
                acc0 = dot2(bch(w[2 * k4]),     bch(U.x), acc0);
                acc1 = dot2(bch(w[2 * k4]),     bch(U.y), acc1);
                acc0 = dot2(bch(w[2 * k4 + 1]), bch(U.z), acc0);
                acc1 = dot2(bch(w[2 * k4 + 1]), bch(U.w), acc1);
            }
#pragma unroll
            for (int k4 = 0; k4 < HD2 / 4; k4++) {
                uint4 U = h2p[k4];
                acc0 = dot2(bch(w[W1_DW + 2 * k4]),     bch(U.x), acc0);
                acc1 = dot2(bch(w[W1_DW + 2 * k4]),     bch(U.y), acc1);
                acc0 = dot2(bch(w[W1_DW + 2 * k4 + 1]), bch(U.z), acc0);
                acc1 = dot2(bch(w[W1_DW + 2 * k4 + 1]), bch(U.w), acc1);
            }
            float z0 = (q == 2) ? 2.f * acc0 : acc0;
            float z1 = (q == 2) ? 2.f * acc1 : acc1;
            float s0 = 1.f / (1.f + __expf(-z0));
            float s1 = 1.f / (1.f + __expf(-z1));
            gates[j] = make_float2((q == 2) ? (2.f * s0 - 1.f) : s0,
                                   (q == 2) ? (2.f * s1 - 1.f) : s1);
        }
        __syncthreads();                       // gates ready

        if (j < HD2) {
            float2 gi = gates[m];
            float2 gf = gates[HD2 + m];
            float2 gg = gates[2 * HD2 + m];
            float2 go = gates[3 * HD2 + m];
            c0 = fmaf(gf.x, c0, gi.x * gg.x);
            c1 = fmaf(gf.y, c1, gi.y * gg.y);
            float t0 = 2.f / (1.f + __expf(-2.f * c0)) - 1.f;
            float t1 = 2.f / (1.f + __expf(-2.f * c1)) - 1.f;
            float h0 = go.x * t0;
            float h1 = go.y * t1;
            float h0a = __shfl_down(h0, 1, 64);
            float h0b = __shfl_down(h0, 2, 64);
            float h0c = __shfl_down(h0, 3, 64);
            float h1a = __shfl_down(h1, 1, 64);
            float h1b = __shfl_down(h1, 2, 64);
            float h1c = __shfl_down(h1, 3, 64);
            if ((m & 3) == 0)
                h2p[m >> 2] = make_uint4(packh(h0, h0a), packh(h1, h1a),
                                         packh(h0b, h0c), packh(h1b, h1c));
            if (t == T_STEPS - 1) {
                h2last[(size_t)(b0 + 0) * HD2 + m] = fmaxf(h0, 0.f);
                h2last[(size_t)(b0 + 1) * HD2 + m] = fmaxf(h1, 0.f);
            }
        }
        // loop top stages h1p(t+1); barrier there covers h2p too
    }
}

// ---------------------------------------------------------------------------
// Head: out[b] = W_l2 @ relu(W_l1 @ h2last[b] + b_l1) + b_l2
// ---------------------------------------------------------------------------
__global__ __launch_bounds__(64)
void head_kernel(const float* __restrict__ h2last,
                 const float* __restrict__ W_l1,
                 const float* __restrict__ b_l1,
                 const float* __restrict__ W_l2,
                 const float* __restrict__ b_l2,
                 float* __restrict__ out)
{
    int b = blockIdx.x * 64 + threadIdx.x;
    if (b >= BATCH) return;
    const float* h = h2last + (size_t)b * HD2;
    float o = b_l2[0];
#pragma unroll
    for (int u = 0; u < 10; u++) {
        float s = b_l1[u];
#pragma unroll
        for (int k = 0; k < HD2; k++) s = fmaf(W_l1[u * HD2 + k], h[k], s);
        o = fmaf(W_l2[u], fmaxf(s, 0.f), o);
    }
    out[b] = o;
}

extern "C" void kernel_launch(void* const* d_in, const int* in_sizes, int n_in,
                              void* d_out, int out_size, void* d_ws, size_t ws_size,
                              hipStream_t stream)
{
    const float* x     = (const float*)d_in[0];
    const float* W_ih1 = (const float*)d_in[1];
    const float* W_hh1 = (const float*)d_in[2];
    const float* b_ih1 = (const float*)d_in[3];
    const float* b_hh1 = (const float*)d_in[4];
    const float* W_ih2 = (const float*)d_in[5];
    const float* W_hh2 = (const float*)d_in[6];
    const float* b_ih2 = (const float*)d_in[7];
    const float* b_hh2 = (const float*)d_in[8];
    const float* W_l1  = (const float*)d_in[9];
    const float* b_l1  = (const float*)d_in[10];
    const float* W_l2  = (const float*)d_in[11];
    const float* b_l2  = (const float*)d_in[12];
    float* out = (float*)d_out;

    // ws layout: h1relu f16 [t][b][k] (84 MB) | h2last f32 | w1t | w2t
    char* p = (char*)d_ws;
    _Float16* h1relu = (_Float16*)p;           p += (size_t)T_STEPS * BATCH * HD1 * 2;
    float* h2last    = (float*)p;              p += (size_t)BATCH * HD2 * 4;
    unsigned int* w1t = (unsigned int*)p;      p += (size_t)W1_DW * NR1 * 4;
    unsigned int* w2t = (unsigned int*)p;

    int prep_n = W1_DW * NR1 + W2_DW * NR2;
    hipLaunchKernelGGL(prep_kernel, dim3((prep_n + 255) / 256), dim3(256), 0, stream,
                       W_hh1, W_ih2, W_hh2, w1t, w2t);
    hipLaunchKernelGGL(lstm1_kernel, dim3(BATCH / NB), dim3(NR1), 0, stream,
                       x, W_ih1, w1t, b_ih1, b_hh1, h1relu);
    hipLaunchKernelGGL(lstm2_kernel, dim3(BATCH / NB), dim3(448), 0, stream,
                       h1relu, w2t, b_ih2, b_hh2, h2last);
    hipLaunchKernelGGL(head_kernel, dim3(BATCH / 64), dim3(64), 0, stream,
                       h2last, W_l1, b_l1, W_l2, b_l2, out);
}

// Round 4
// 1713.616 us; speedup vs baseline: 1.0892x; 1.0892x over previous
//
#include <hip/hip_runtime.h>
#include <hip/hip_bf16.h>

#define T_STEPS 512
#define BATCH   1024
#define HD1     80
#define HD2     100
#define NB      2       // batches per block (lstm2)

#define W1_DW   (HD1 / 2)              // 40 packed dwords per lstm1 row
#define W2_DW   ((HD1 + HD2) / 2)      // 90 packed dwords per lstm2 row
#define NR1     (4 * HD1)              // 320 rows
#define NR2     (4 * HD2)              // 400 rows

typedef _Float16 half2_t __attribute__((ext_vector_type(2)));

union HU { unsigned int u; half2_t h; };
static __device__ __forceinline__ half2_t bch(unsigned int u) { HU x; x.u = u; return x.h; }
static __device__ __forceinline__ unsigned int bcu(half2_t h) { HU x; x.h = h; return x.u; }

static __device__ __forceinline__ float dot2(half2_t a, half2_t b, float c) {
    return __builtin_amdgcn_fdot2(a, b, c, false);
}

static __device__ __forceinline__ unsigned int packh(float a, float b) {
    half2_t p; p.x = (_Float16)a; p.y = (_Float16)b; return bcu(p);
}

// ---------------------------------------------------------------------------
// Prep: pack weights to f16 dwords, transposed [dword][row] for coalescing.
// ---------------------------------------------------------------------------
__global__ __launch_bounds__(256)
void prep_kernel(const float* __restrict__ W_hh1,
                 const float* __restrict__ W_ih2,
                 const float* __restrict__ W_hh2,
                 unsigned int* __restrict__ w1t,
                 unsigned int* __restrict__ w2t)
{
    int i = blockIdx.x * 256 + threadIdx.x;
    if (i < W1_DW * NR1) {
        int d = i / NR1, j = i % NR1;
        w1t[i] = packh(W_hh1[j * HD1 + 2 * d], W_hh1[j * HD1 + 2 * d + 1]);
    } else if (i < W1_DW * NR1 + W2_DW * NR2) {
        int k = i - W1_DW * NR1;
        int d = k / NR2, j = k % NR2;
        unsigned int p;
        if (d < W1_DW)
            p = packh(W_ih2[j * HD1 + 2 * d], W_ih2[j * HD1 + 2 * d + 1]);
        else {
            int dd = d - W1_DW;
            p = packh(W_hh2[j * HD2 + 2 * dd], W_hh2[j * HD2 + 2 * dd + 1]);
        }
        w2t[k] = p;
    }
}

// ---------------------------------------------------------------------------
// Phase 1: LSTM layer 1, ONE batch per block (1024 blocks x 320 threads).
// Thread j owns gate-row j; 40 weight dwords in VGPRs (unconditional loads).
// h state: uint4[10] in LDS (8 f16 per entry). 2 indep acc chains.
// Writes relu(h1) f16 to ws, layout [t][b][k].
// ---------------------------------------------------------------------------
__global__ __launch_bounds__(NR1, 4)
void lstm1_kernel(const float* __restrict__ x,
                  const float* __restrict__ W_ih1,
                  const unsigned int* __restrict__ w1t,
                  const float* __restrict__ b_ih1,
                  const float* __restrict__ b_hh1,
                  _Float16* __restrict__ h1relu)
{
    const int j = threadIdx.x;
    const int b = blockIdx.x;
    const int q = j / HD1;
    const int m = j % HD1;

    unsigned int w[W1_DW];
#pragma unroll
    for (int d = 0; d < W1_DW; d++) w[d] = w1t[d * NR1 + j];
    const float wih  = W_ih1[j];
    const float bias = b_ih1[j] + b_hh1[j];

    __shared__ uint4 hp[HD1 / 8];     // 10 entries, 8 f16 values each
    __shared__ float gates[NR1];
    __shared__ float xs[T_STEPS];

    if (j < HD1 / 8) hp[j] = make_uint4(0u, 0u, 0u, 0u);
    for (int idx = j; idx < T_STEPS; idx += NR1)
        xs[idx] = x[(size_t)b * T_STEPS + idx];
    float c = 0.f;
    __syncthreads();

    for (int t = 0; t < T_STEPS; t++) {
        float accP = fmaf(wih, xs[t], bias);
        float accQ = 0.f;
#pragma unroll
        for (int k4 = 0; k4 < HD1 / 8; k4++) {
            uint4 U = hp[k4];
            accP = dot2(bch(w[4 * k4 + 0]), bch(U.x), accP);
            accQ = dot2(bch(w[4 * k4 + 1]), bch(U.y), accQ);
            accP = dot2(bch(w[4 * k4 + 2]), bch(U.z), accP);
            accQ = dot2(bch(w[4 * k4 + 3]), bch(U.w), accQ);
        }
        float z = accP + accQ;
        z = (q == 2) ? 2.f * z : z;
        float s = 1.f / (1.f + __expf(-z));
        gates[j] = (q == 2) ? (2.f * s - 1.f) : s;
        __syncthreads();                      // gates ready

        if (j < HD1) {
            float gi = gates[m];
            float gf = gates[HD1 + m];
            float gg = gates[2 * HD1 + m];
            float go = gates[3 * HD1 + m];
            c = fmaf(gf, c, gi * gg);
            float th = 2.f / (1.f + __expf(-2.f * c)) - 1.f;
            float h = go * th;
            float hn = __shfl_down(h, 1, 64);
            if ((m & 1) == 0) {
                ((unsigned int*)hp)[m >> 1] = packh(h, hn);
                *(unsigned int*)(h1relu + ((size_t)t * BATCH + b) * HD1 + m) =
                    packh(fmaxf(h, 0.f), fmaxf(hn, 0.f));
            }
        }
        __syncthreads();                      // hp(t+1) ready
    }
}

// ---------------------------------------------------------------------------
// Phase 2: LSTM layer 2. 512 blocks x 512 threads, 2 batches/block.
// Rows 0..399 own gate-rows; 90 weight dwords in VGPRs (unconditional,
// clamped loads so SROA can promote). Threads 400..479 are h1 stagers with
// 1-step register prefetch. Dot loops run on ALL threads (uniform); only
// the gates write is guarded. 4 indep acc chains. 2 barriers/step.
// ---------------------------------------------------------------------------
__global__ __launch_bounds__(512, 4)
void lstm2_kernel(const _Float16* __restrict__ h1relu,
                  const unsigned int* __restrict__ w2t,
                  const float* __restrict__ b_ih2,
                  const float* __restrict__ b_hh2,
                  float* __restrict__ h2last)
{
    const int j  = threadIdx.x;
    const int b0 = blockIdx.x * NB;
    const int jr = (j < NR2) ? j : (NR2 - 1);   // clamp: loads unconditional
    const bool rowActive = (j < NR2);
    const int q = jr / HD2;
    const int m = jr % HD2;

    unsigned int w[W2_DW];
#pragma unroll
    for (int d = 0; d < W2_DW; d++) w[d] = w2t[d * NR2 + jr];
    const float bias = b_ih2[jr] + b_hh2[jr];

    __shared__ uint4  h1p[HD1 / 4];    // 20 entries: {b0 pair, b1 pair, b0 pair, b1 pair}
    __shared__ uint4  h2p[HD2 / 4];    // 25 entries, same layout
    __shared__ float2 gates[NR2];

    if (j < HD2 / 4) h2p[j] = make_uint4(0u, 0u, 0u, 0u);
    float c0 = 0.f, c1 = 0.f;

    // stagers: threads 400..479
    const int  sj = j - NR2;
    const bool stager = (sj >= 0) && (sj < NB * W1_DW);
    const int  pb  = (sj >= 0 ? sj : 0) / W1_DW;
    const int  pk2 = (sj >= 0 ? sj : 0) % W1_DW;
    const int  sidx = 4 * (pk2 >> 1) + 2 * (pk2 & 1) + pb;
    unsigned int pf = 0;
    if (stager)
        pf = *(const unsigned int*)(h1relu + ((size_t)b0 + pb) * HD1 + 2 * pk2);

    for (int t = 0; t < T_STEPS; t++) {
        if (stager)
            ((unsigned int*)h1p)[sidx] = pf;   // stage h1(t)
        __syncthreads();                       // h1p(t) + h2p(t) ready

        if (stager && t + 1 < T_STEPS)
            pf = *(const unsigned int*)(h1relu +
                     ((size_t)(t + 1) * BATCH + b0 + pb) * HD1 + 2 * pk2);

        // dots on ALL threads (uniform control flow; garbage for j>=400)
        float a0P = bias, a0Q = 0.f, a1P = bias, a1Q = 0.f;
#pragma unroll
        for (int k4 = 0; k4 < HD1 / 4; k4++) {
            uint4 U = h1p[k4];
            a0P = dot2(bch(w[2 * k4]),     bch(U.x), a0P);
            a1P = dot2(bch(w[2 * k4]),     bch(U.y), a1P);
            a0Q = dot2(bch(w[2 * k4 + 1]), bch(U.z), a0Q);
            a1Q = dot2(bch(w[2 * k4 + 1]), bch(U.w), a1Q);
        }
#pragma unroll
        for (int k4 = 0; k4 < HD2 / 4; k4++) {
            uint4 U = h2p[k4];
            a0P = dot2(bch(w[W1_DW + 2 * k4]),     bch(U.x), a0P);
            a1P = dot2(bch(w[W1_DW + 2 * k4]),     bch(U.y), a1P);
            a0Q = dot2(bch(w[W1_DW + 2 * k4 + 1]), bch(U.z), a0Q);
            a1Q = dot2(bch(w[W1_DW + 2 * k4 + 1]), bch(U.w), a1Q);
        }
        float z0 = a0P + a0Q;
        float z1 = a1P + a1Q;
        z0 = (q == 2) ? 2.f * z0 : z0;
        z1 = (q == 2) ? 2.f * z1 : z1;
        float s0 = 1.f / (1.f + __expf(-z0));
        float s1 = 1.f / (1.f + __expf(-z1));
        if (rowActive)
            gates[j] = make_float2((q == 2) ? (2.f * s0 - 1.f) : s0,
                                   (q == 2) ? (2.f * s1 - 1.f) : s1);
        __syncthreads();                       // gates ready

        if (j < HD2) {
            float2 gi = gates[m];
            float2 gf = gates[HD2 + m];
            float2 gg = gates[2 * HD2 + m];
            float2 go = gates[3 * HD2 + m];
            c0 = fmaf(gf.x, c0, gi.x * gg.x);
            c1 = fmaf(gf.y, c1, gi.y * gg.y);
            float t0 = 2.f / (1.f + __expf(-2.f * c0)) - 1.f;
            float t1 = 2.f / (1.f + __expf(-2.f * c1)) - 1.f;
            float h0 = go.x * t0;
            float h1 = go.y * t1;
            float h0n = __shfl_down(h0, 1, 64);
            float h1n = __shfl_down(h1, 1, 64);
            if ((m & 1) == 0) {
                int p = m >> 1;
                int idx0 = 4 * (p >> 1) + 2 * (p & 1);   // even → uint2-aligned
                ((uint2*)h2p)[idx0 >> 1] =
                    make_uint2(packh(h0, h0n), packh(h1, h1n));
            }
            if (t == T_STEPS - 1) {
                h2last[(size_t)(b0 + 0) * HD2 + m] = fmaxf(h0, 0.f);
                h2last[(size_t)(b0 + 1) * HD2 + m] = fmaxf(h1, 0.f);
            }
        }
        // next loop-top stage + barrier covers h2p visibility
    }
}

// ---------------------------------------------------------------------------
// Head: out[b] = W_l2 @ relu(W_l1 @ h2last[b] + b_l1) + b_l2
// ---------------------------------------------------------------------------
__global__ __launch_bounds__(64)
void head_kernel(const float* __restrict__ h2last,
                 const float* __restrict__ W_l1,
                 const float* __restrict__ b_l1,
                 const float* __restrict__ W_l2,
                 const float* __restrict__ b_l2,
                 float* __restrict__ out)
{
    int b = blockIdx.x * 64 + threadIdx.x;
    if (b >= BATCH) return;
    const float* h = h2last + (size_t)b * HD2;
    float o = b_l2[0];
#pragma unroll
    for (int u = 0; u < 10; u++) {
        float s = b_l1[u];
#pragma unroll
        for (int k = 0; k < HD2; k++) s = fmaf(W_l1[u * HD2 + k], h[k], s);
        o = fmaf(W_l2[u], fmaxf(s, 0.f), o);
    }
    out[b] = o;
}

extern "C" void kernel_launch(void* const* d_in, const int* in_sizes, int n_in,
                              void* d_out, int out_size, void* d_ws, size_t ws_size,
                              hipStream_t stream)
{
    const float* x     = (const float*)d_in[0];
    const float* W_ih1 = (const float*)d_in[1];
    const float* W_hh1 = (const float*)d_in[2];
    const float* b_ih1 = (const float*)d_in[3];
    const float* b_hh1 = (const float*)d_in[4];
    const float* W_ih2 = (const float*)d_in[5];
    const float* W_hh2 = (const float*)d_in[6];
    const float* b_ih2 = (const float*)d_in[7];
    const float* b_hh2 = (const float*)d_in[8];
    const float* W_l1  = (const float*)d_in[9];
    const float* b_l1  = (const float*)d_in[10];
    const float* W_l2  = (const float*)d_in[11];
    const float* b_l2  = (const float*)d_in[12];
    float* out = (float*)d_out;

    // ws layout: h1relu f16 [t][b][k] (84 MB) | h2last f32 | w1t | w2t
    char* p = (char*)d_ws;
    _Float16* h1relu = (_Float16*)p;           p += (size_t)T_STEPS * BATCH * HD1 * 2;
    float* h2last    = (float*)p;              p += (size_t)BATCH * HD2 * 4;
    unsigned int* w1t = (unsigned int*)p;      p += (size_t)W1_DW * NR1 * 4;
    unsigned int* w2t = (unsigned int*)p;

    int prep_n = W1_DW * NR1 + W2_DW * NR2;
    hipLaunchKernelGGL(prep_kernel, dim3((prep_n + 255) / 256), dim3(256), 0, stream,
                       W_hh1, W_ih2, W_hh2, w1t, w2t);
    hipLaunchKernelGGL(lstm1_kernel, dim3(BATCH), dim3(NR1), 0, stream,
                       x, W_ih1, w1t, b_ih1, b_hh1, h1relu);
    hipLaunchKernelGGL(lstm2_kernel, dim3(BATCH / NB), dim3(512), 0, stream,
                       h1relu, w2t, b_ih2, b_hh2, h2last);
    hipLaunchKernelGGL(head_kernel, dim3(BATCH / 64), dim3(64), 0, stream,
                       h2last, W_l1, b_l1, W_l2, b_l2, out);
}